// Round 2
// baseline (211.315 us; speedup 1.0000x reference)
//
#include <hip/hip_runtime.h>
#include <hip/hip_bf16.h>
#include <stdint.h>

#define BB     8
#define CC     320
#define NN     4096
#define SKV    77
#define HEADS  8
#define INNER  512
#define SCALE  0.125f

typedef float f32x4  __attribute__((ext_vector_type(4)));
typedef short bf16x8 __attribute__((ext_vector_type(8)));
typedef short s16x4  __attribute__((ext_vector_type(4)));

static __device__ __forceinline__ short f2bf(float f) {
  unsigned u = __float_as_uint(f);
  return (short)((u + 0x7fffu + ((u >> 16) & 1u)) >> 16);
}

// ---------------------------------------------------------------------------
// prep: kv->bf16 | Wk,Wv,Wq(x SCALE),Wo tiled transposes | zero V_ws pad.
// blocks: [0,616) kv | [616,872) Wk/Wv | [872,912) Wq | [912,952) Wo |
// [952,1192) zero V_ws
// ---------------------------------------------------------------------------
__global__ __launch_bounds__(256) void prep_kernel(
    const float* __restrict__ kv, const float* __restrict__ Wk,
    const float* __restrict__ Wv, const float* __restrict__ Wq,
    const float* __restrict__ Wo, short* __restrict__ kv_bf,
    short* __restrict__ Wk_t, short* __restrict__ Wv_t,
    short* __restrict__ Wq_t, short* __restrict__ Wo_t,
    unsigned* __restrict__ zero_base) {
  __shared__ float T[64 * 65];
  const int blk = blockIdx.x, t = threadIdx.x;
  if (blk < 616) {
    const int base = blk * 1024;
    #pragma unroll
    for (int i = 0; i < 4; ++i) kv_bf[base + i*256 + t] = f2bf(kv[base + i*256 + t]);
    return;
  }
  if (blk >= 952) {              // zero V_ws (pad cols read by PV must be 0)
    const int base = (blk - 952) * 1024;
    #pragma unroll
    for (int i = 0; i < 4; ++i) zero_base[base + i*256 + t] = 0u;
    return;
  }
  const float* src; short* dst; int RS, CS, kt, ct; float scl = 1.0f;
  if (blk < 872) {               // Wk/Wv: [1024][512] -> [512][1024]
    const int tile = blk - 616;
    const bool isK = tile < 128;
    const int tt = isK ? tile : tile - 128;
    src = isK ? Wk : Wv; dst = isK ? Wk_t : Wv_t;
    RS = 1024; CS = 512; kt = tt >> 3; ct = tt & 7;
  } else if (blk < 912) {        // Wq: [320][512] -> [512][320], x SCALE
    const int tt = blk - 872;
    src = Wq; dst = Wq_t; RS = 320; CS = 512; kt = tt >> 3; ct = tt & 7;
    scl = SCALE;
  } else {                       // Wo: [512][320] -> [320][512]
    const int tt = blk - 912;
    src = Wo; dst = Wo_t; RS = 512; CS = 320; kt = tt / 5; ct = tt % 5;
  }
  const int cl = t & 63, rb = t >> 6;
  #pragma unroll
  for (int i = 0; i < 16; ++i)
    T[(rb + i*4)*65 + cl] = src[(size_t)(kt*64 + rb + i*4)*CS + ct*64 + cl];
  __syncthreads();
  #pragma unroll
  for (int i = 0; i < 16; ++i) {
    const int nl = rb + i*4;
    dst[(size_t)(ct*64 + nl)*RS + kt*64 + cl] = f2bf(T[cl*65 + nl] * scl);
  }
}

// ---------------------------------------------------------------------------
// kvproj: [616,1024]bf16 @ Wk_t/Wv_t -> K_ws [b][h][80][64], V_ws [b][h][64][96]
// ---------------------------------------------------------------------------
__global__ __launch_bounds__(256) void kvproj_kernel(
    const short* __restrict__ kv_bf, const short* __restrict__ Wk_t,
    const short* __restrict__ Wv_t, short* __restrict__ K_ws,
    short* __restrict__ V_ws) {
  const int t = threadIdx.x, w = t >> 6, lane = t & 63;
  const int l15 = lane & 15, q = lane >> 4;
  const int m0 = (blockIdx.x * 4 + w) * 16;
  const int y = blockIdx.y;
  const bool isK = (y < 8);
  const int h = y & 7;
  const short* __restrict__ Wt = isK ? Wk_t : Wv_t;
  const int arow = (m0 + l15 < 616) ? (m0 + l15) : 615;

  const f32x4 z = {0.f, 0.f, 0.f, 0.f};
  f32x4 acc[4] = {z, z, z, z};
  for (int k0 = 0; k0 < 1024; k0 += 32) {
    const bf16x8 a = *(const bf16x8*)(kv_bf + arow*1024 + k0 + q*8);
    #pragma unroll
    for (int nt = 0; nt < 4; ++nt) {
      const int n = h*64 + nt*16 + l15;
      const bf16x8 bfr = *(const bf16x8*)(Wt + n*1024 + k0 + q*8);
      acc[nt] = __builtin_amdgcn_mfma_f32_16x16x32_bf16(a, bfr, acc[nt], 0, 0, 0);
    }
  }
  #pragma unroll
  for (int nt = 0; nt < 4; ++nt) {
    const int d = nt*16 + l15;
    #pragma unroll
    for (int r = 0; r < 4; ++r) {
      const int row = m0 + q*4 + r;
      if (row < 616) {
        const int b = (int)(((unsigned)row * 54472u) >> 22);   // row/77
        const int s = row - b*77;
        if (isK) K_ws[((b*8 + h)*80 + s)*64 + d] = f2bf(acc[nt][r]);
        else     V_ws[((b*8 + h)*64 + d)*96 + s] = f2bf(acc[nt][r]);
      }
    }
  }
}

// ---------------------------------------------------------------------------
// fused v2: qproj + attention + outproj for 32 tokens per block. 1024 blocks.
// Weights read DIRECTLY from L2 (no LDS staging, no per-K-step barriers).
// Phase 0: query[b][c][n0:n0+32] fp32 -> A_lds[tok][c] bf16 (pad 328).
// Phase 1: Q[32x512] = A @ Wq_t^T; wave w owns j in [128w,128w+128) = heads
//          {2w,2w+1}; 2-deep reg double-buffered K-loop, barrier-free.
// Phase 2: per-wave attention over its 2 heads; O overwrites Q in Q_lds.
// Phase 3: out[320c x 32n] = Wo_t @ O^T; Wo_t from L2, O from LDS;
//          barrier-free K-loop; coalesced fp32 epilogue + bias.
// LDS: Q_lds 33,280 B + U 26,624 B (A-tile | P-scratch union) = 59,904 B
//      -> 2 blocks/CU, 8 waves/CU.
// ---------------------------------------------------------------------------
__global__ __launch_bounds__(256, 2) void fused_kernel(
    const float* __restrict__ query, const short* __restrict__ Wq_t,
    const short* __restrict__ K_ws, const short* __restrict__ V_ws,
    const short* __restrict__ Wo_t, const float* __restrict__ bo,
    float* __restrict__ out) {
  const int t = threadIdx.x, w = t >> 6, lane = t & 63;
  const int l15 = lane & 15, q = lane >> 4;
  const int b = blockIdx.x >> 7;
  const int n0 = (blockIdx.x & 127) * 32;

  __shared__ __align__(16) short Q_lds[32 * 520];  // Q then O, token-major
  __shared__ __align__(16) short U[13312];         // A[32][328] | P 4x[32][104]

  const f32x4 z = {0.f, 0.f, 0.f, 0.f};

  // ---------------- phase 0: query -> A_lds (transposed, bf16) ----------
  {
    const float* qb = query + (size_t)b * CC * NN + n0;
    #pragma unroll
    for (int i = 0; i < 10; ++i) {
      const int f = i * 256 + t;
      const int c = f >> 3, n4 = (f & 7) * 4;
      const f32x4 v = *(const f32x4*)(qb + (size_t)c * NN + n4);
      #pragma unroll
      for (int j = 0; j < 4; ++j)
        U[(n4 + j) * 328 + c] = f2bf(v[j]);
    }
  }
  __syncthreads();

  // ---------------- phase 1: Q = A @ Wq^T (Wq from L2) ----------
  {
    f32x4 acc[2][8];
    #pragma unroll
    for (int mt = 0; mt < 2; ++mt)
      #pragma unroll
      for (int nt = 0; nt < 8; ++nt) acc[mt][nt] = z;

    const short* __restrict__ Wb = Wq_t + (size_t)(w * 128) * 320;
    auto ld1 = [&](int it, bf16x8 (&A)[2], bf16x8 (&B)[8]) {
      const int k0 = it * 32;
      #pragma unroll
      for (int x = 0; x < 2; ++x)
        A[x] = *(const bf16x8*)(U + (x * 16 + l15) * 328 + k0 + q * 8);
      #pragma unroll
      for (int x = 0; x < 8; ++x)
        B[x] = *(const bf16x8*)(Wb + (size_t)(x * 16 + l15) * 320 + k0 + q * 8);
    };
    bf16x8 aP[2], bP[8], aN[2], bN[8];
    ld1(0, aP, bP);
    #pragma unroll
    for (int it = 0; it < 10; ++it) {
      if (it + 1 < 10) ld1(it + 1, aN, bN);
      #pragma unroll
      for (int mt = 0; mt < 2; ++mt)
        #pragma unroll
        for (int nt = 0; nt < 8; ++nt)
          acc[mt][nt] = __builtin_amdgcn_mfma_f32_16x16x32_bf16(aP[mt], bP[nt], acc[mt][nt], 0, 0, 0);
      #pragma unroll
      for (int x = 0; x < 2; ++x) aP[x] = aN[x];
      #pragma unroll
      for (int x = 0; x < 8; ++x) bP[x] = bN[x];
    }
    #pragma unroll
    for (int mt = 0; mt < 2; ++mt)
      #pragma unroll
      for (int r = 0; r < 4; ++r) {
        const int tok = mt * 16 + q * 4 + r;
        #pragma unroll
        for (int nt = 0; nt < 8; ++nt)
          Q_lds[tok * 520 + w * 128 + nt * 16 + l15] = f2bf(acc[mt][nt][r]);
      }
  }
  __syncthreads();   // U about to be reused as P scratch

  // ---------------- phase 2: attention (wave w -> heads 2w,2w+1) --------
  {
    short* scrw = U + w * 3328;       // 32 x 104 bf16 per wave
    // zero P cols [80,96): PV f=2 reads to col 95
    for (int i = lane; i < 256; i += 64)
      *(unsigned*)(scrw + (i >> 3) * 104 + 80 + (i & 7) * 2) = 0u;

    #pragma unroll
    for (int hh = 0; hh < 2; ++hh) {
      const int h = w * 2 + hh;
      const short* __restrict__ Kh = K_ws + (size_t)(b * 8 + h) * 80 * 64;
      const short* __restrict__ Vh = V_ws + (size_t)(b * 8 + h) * 64 * 96;

      f32x4 qk[2][5];
      #pragma unroll
      for (int nt = 0; nt < 2; ++nt)
        #pragma unroll
        for (int st = 0; st < 5; ++st) qk[nt][st] = z;
      #pragma unroll
      for (int f = 0; f < 2; ++f) {
        bf16x8 bq[2];
        #pragma unroll
        for (int nt = 0; nt < 2; ++nt)
          bq[nt] = *(const bf16x8*)(Q_lds + (nt * 16 + l15) * 520 + h * 64 + f * 32 + q * 8);
        #pragma unroll
        for (int st = 0; st < 5; ++st) {
          const bf16x8 a = *(const bf16x8*)(Kh + (st * 16 + l15) * 64 + f * 32 + q * 8);
          #pragma unroll
          for (int nt = 0; nt < 2; ++nt)
            qk[nt][st] = __builtin_amdgcn_mfma_f32_16x16x32_bf16(a, bq[nt], qk[nt][st], 0, 0, 0);
        }
      }

      #pragma unroll
      for (int nt = 0; nt < 2; ++nt) {
        float mx = -1e30f;
        #pragma unroll
        for (int st = 0; st < 5; ++st)
          #pragma unroll
          for (int r = 0; r < 4; ++r) {
            const int s = st * 16 + q * 4 + r;
            const float vv = (s < SKV) ? qk[nt][st][r] : -1e30f;
            qk[nt][st][r] = vv;
            mx = fmaxf(mx, vv);
          }
        mx = fmaxf(mx, __shfl_xor(mx, 16));
        mx = fmaxf(mx, __shfl_xor(mx, 32));
        float sum = 0.f;
        #pragma unroll
        for (int st = 0; st < 5; ++st)
          #pragma unroll
          for (int r = 0; r < 4; ++r) {
            const int s = st * 16 + q * 4 + r;
            const float e = (s < SKV) ? __expf(qk[nt][st][r] - mx) : 0.f;
            qk[nt][st][r] = e;
            sum += e;
          }
        sum += __shfl_xor(sum, 16);
        sum += __shfl_xor(sum, 32);
        const float inv = 1.0f / sum;
        #pragma unroll
        for (int st = 0; st < 5; ++st) {
          s16x4 pv;
          #pragma unroll
          for (int r = 0; r < 4; ++r) pv[r] = f2bf(qk[nt][st][r] * inv);
          *(s16x4*)(scrw + (nt * 16 + l15) * 104 + st * 16 + q * 4) = pv;
        }
      }

      f32x4 ov[2][4];
      #pragma unroll
      for (int nt = 0; nt < 2; ++nt)
        #pragma unroll
        for (int dt = 0; dt < 4; ++dt) ov[nt][dt] = z;
      #pragma unroll
      for (int f = 0; f < 3; ++f) {
        bf16x8 bp[2];
        #pragma unroll
        for (int nt = 0; nt < 2; ++nt)
          bp[nt] = *(const bf16x8*)(scrw + (nt * 16 + l15) * 104 + f * 32 + q * 8);
        #pragma unroll
        for (int dt = 0; dt < 4; ++dt) {
          const bf16x8 a = *(const bf16x8*)(Vh + (dt * 16 + l15) * 96 + f * 32 + q * 8);
          #pragma unroll
          for (int nt = 0; nt < 2; ++nt)
            ov[nt][dt] = __builtin_amdgcn_mfma_f32_16x16x32_bf16(a, bp[nt], ov[nt][dt], 0, 0, 0);
        }
      }
      // O overwrites Q in place (cols h*64..h*64+63, this wave's own range)
      #pragma unroll
      for (int nt = 0; nt < 2; ++nt)
        #pragma unroll
        for (int dt = 0; dt < 4; ++dt) {
          s16x4 pv;
          #pragma unroll
          for (int r = 0; r < 4; ++r) pv[r] = f2bf(ov[nt][dt][r]);
          *(s16x4*)(Q_lds + (nt * 16 + l15) * 520 + h * 64 + dt * 16 + q * 4) = pv;
        }
    }
  }
  __syncthreads();   // O complete

  // ---------------- phase 3: out = Wo_t @ O^T + bias (Wo from L2) -------
  {
    f32x4 oc[5][2];
    #pragma unroll
    for (int mt = 0; mt < 5; ++mt)
      #pragma unroll
      for (int nt = 0; nt < 2; ++nt) oc[mt][nt] = z;

    const short* __restrict__ Wa = Wo_t + (size_t)(w * 80) * 512;
    auto ld3 = [&](int it, bf16x8 (&A)[5], bf16x8 (&B)[2]) {
      const int k0 = it * 32;
      #pragma unroll
      for (int x = 0; x < 5; ++x)
        A[x] = *(const bf16x8*)(Wa + (size_t)(x * 16 + l15) * 512 + k0 + q * 8);
      #pragma unroll
      for (int x = 0; x < 2; ++x)
        B[x] = *(const bf16x8*)(Q_lds + (x * 16 + l15) * 520 + k0 + q * 8);
    };
    bf16x8 aP[5], bP[2], aN[5], bN[2];
    ld3(0, aP, bP);
    #pragma unroll
    for (int it = 0; it < 16; ++it) {
      if (it + 1 < 16) ld3(it + 1, aN, bN);
      #pragma unroll
      for (int mt = 0; mt < 5; ++mt)
        #pragma unroll
        for (int nt = 0; nt < 2; ++nt)
          oc[mt][nt] = __builtin_amdgcn_mfma_f32_16x16x32_bf16(aP[mt], bP[nt], oc[mt][nt], 0, 0, 0);
      #pragma unroll
      for (int x = 0; x < 5; ++x) aP[x] = aN[x];
      #pragma unroll
      for (int x = 0; x < 2; ++x) bP[x] = bN[x];
    }
    #pragma unroll
    for (int mt = 0; mt < 5; ++mt)
      #pragma unroll
      for (int r = 0; r < 4; ++r) {
        const int c = w * 80 + mt * 16 + q * 4 + r;
        const float bv = bo[c];
        float* rowp = out + ((size_t)(b * CC + c)) * NN + n0;
        #pragma unroll
        for (int nt = 0; nt < 2; ++nt)
          rowp[nt * 16 + l15] = oc[mt][nt][r] + bv;
      }
  }
}

// ---------------------------------------------------------------------------
extern "C" void kernel_launch(void* const* d_in, const int* in_sizes, int n_in,
                              void* d_out, int out_size, void* d_ws, size_t ws_size,
                              hipStream_t stream) {
  const float* query = (const float*)d_in[0];
  const float* kv    = (const float*)d_in[1];
  const float* Wq    = (const float*)d_in[2];
  const float* Wk    = (const float*)d_in[3];
  const float* Wv    = (const float*)d_in[4];
  const float* Wo    = (const float*)d_in[5];
  const float* bo    = (const float*)d_in[6];
  float* out = (float*)d_out;

  char* p = (char*)d_ws;
  short* K_ws  = (short*)(p);             //   819,200 B [8][8][80][64]
  short* V_ws  = (short*)(p +   819200);  //   983,040 B [8][8][64][96]
  short* Wq_t  = (short*)(p +  1802240);  //   327,680 B [512][320] (x SCALE)
  short* Wo_t  = (short*)(p +  2129920);  //   327,680 B [320][512]
  short* kv_bf = (short*)(p +  2457600);  //  1,261,568 B [616][1024]
  short* Wk_t  = (short*)(p +  3719168);  //  1,048,576 B [512][1024]
  short* Wv_t  = (short*)(p +  4767744);  //  1,048,576 B [512][1024]

  prep_kernel<<<1192, 256, 0, stream>>>(kv, Wk, Wv, Wq, Wo, kv_bf,
                                        Wk_t, Wv_t, Wq_t, Wo_t,
                                        (unsigned*)V_ws);
  kvproj_kernel<<<dim3(10, 16), 256, 0, stream>>>(kv_bf, Wk_t, Wv_t, K_ws, V_ws);
  fused_kernel<<<1024, 256, 0, stream>>>(query, Wq_t, K_ws, V_ws, Wo_t, bo, out);
}

// Round 3
// 176.786 us; speedup vs baseline: 1.1953x; 1.1953x over previous
//
#include <hip/hip_runtime.h>
#include <hip/hip_bf16.h>
#include <stdint.h>

#define BB     8
#define CC     320
#define NN     4096
#define SKV    77
#define HEADS  8
#define INNER  512
#define SCALE  0.125f

typedef float f32x4  __attribute__((ext_vector_type(4)));
typedef short bf16x8 __attribute__((ext_vector_type(8)));
typedef short s16x4  __attribute__((ext_vector_type(4)));

static __device__ __forceinline__ short f2bf(float f) {
  unsigned u = __float_as_uint(f);
  return (short)((u + 0x7fffu + ((u >> 16) & 1u)) >> 16);
}

// async global->LDS 16B copy; LDS dest is wave-uniform base + lane*16.
static __device__ __forceinline__ void gll16(void* lds, const void* g) {
  auto gp = reinterpret_cast<const uint32_t __attribute__((address_space(1)))*>(
      reinterpret_cast<uintptr_t>(g));
  auto lp = reinterpret_cast<uint32_t __attribute__((address_space(3)))*>(
      reinterpret_cast<uintptr_t>(lds));
  __builtin_amdgcn_global_load_lds(gp, lp, 16, 0, 0);
}

// ---------------------------------------------------------------------------
// prep: kv->bf16 | Wk,Wv,Wq(x SCALE),Wo tiled transposes | zero V_ws pad.
// blocks: [0,616) kv | [616,872) Wk/Wv | [872,912) Wq | [912,952) Wo |
// [952,1192) zero V_ws
// ---------------------------------------------------------------------------
__global__ __launch_bounds__(256) void prep_kernel(
    const float* __restrict__ kv, const float* __restrict__ Wk,
    const float* __restrict__ Wv, const float* __restrict__ Wq,
    const float* __restrict__ Wo, short* __restrict__ kv_bf,
    short* __restrict__ Wk_t, short* __restrict__ Wv_t,
    short* __restrict__ Wq_t, short* __restrict__ Wo_t,
    unsigned* __restrict__ zero_base) {
  __shared__ float T[64 * 65];
  const int blk = blockIdx.x, t = threadIdx.x;
  if (blk < 616) {
    const int base = blk * 1024;
    #pragma unroll
    for (int i = 0; i < 4; ++i) kv_bf[base + i*256 + t] = f2bf(kv[base + i*256 + t]);
    return;
  }
  if (blk >= 952) {              // zero V_ws (pad cols read by PV must be 0)
    const int base = (blk - 952) * 1024;
    #pragma unroll
    for (int i = 0; i < 4; ++i) zero_base[base + i*256 + t] = 0u;
    return;
  }
  const float* src; short* dst; int RS, CS, kt, ct; float scl = 1.0f;
  if (blk < 872) {               // Wk/Wv: [1024][512] -> [512][1024]
    const int tile = blk - 616;
    const bool isK = tile < 128;
    const int tt = isK ? tile : tile - 128;
    src = isK ? Wk : Wv; dst = isK ? Wk_t : Wv_t;
    RS = 1024; CS = 512; kt = tt >> 3; ct = tt & 7;
  } else if (blk < 912) {        // Wq: [320][512] -> [512][320], x SCALE
    const int tt = blk - 872;
    src = Wq; dst = Wq_t; RS = 320; CS = 512; kt = tt >> 3; ct = tt & 7;
    scl = SCALE;
  } else {                       // Wo: [512][320] -> [320][512]
    const int tt = blk - 912;
    src = Wo; dst = Wo_t; RS = 512; CS = 320; kt = tt / 5; ct = tt % 5;
  }
  const int cl = t & 63, rb = t >> 6;
  #pragma unroll
  for (int i = 0; i < 16; ++i)
    T[(rb + i*4)*65 + cl] = src[(size_t)(kt*64 + rb + i*4)*CS + ct*64 + cl];
  __syncthreads();
  #pragma unroll
  for (int i = 0; i < 16; ++i) {
    const int nl = rb + i*4;
    dst[(size_t)(ct*64 + nl)*RS + kt*64 + cl] = f2bf(T[cl*65 + nl] * scl);
  }
}

// ---------------------------------------------------------------------------
// kvproj: [616,1024]bf16 @ Wk_t/Wv_t -> K_ws [b][h][80][64], V_ws [b][h][64][96]
// ---------------------------------------------------------------------------
__global__ __launch_bounds__(256) void kvproj_kernel(
    const short* __restrict__ kv_bf, const short* __restrict__ Wk_t,
    const short* __restrict__ Wv_t, short* __restrict__ K_ws,
    short* __restrict__ V_ws) {
  const int t = threadIdx.x, w = t >> 6, lane = t & 63;
  const int l15 = lane & 15, q = lane >> 4;
  const int m0 = (blockIdx.x * 4 + w) * 16;
  const int y = blockIdx.y;
  const bool isK = (y < 8);
  const int h = y & 7;
  const short* __restrict__ Wt = isK ? Wk_t : Wv_t;
  const int arow = (m0 + l15 < 616) ? (m0 + l15) : 615;

  const f32x4 z = {0.f, 0.f, 0.f, 0.f};
  f32x4 acc[4] = {z, z, z, z};
  for (int k0 = 0; k0 < 1024; k0 += 32) {
    const bf16x8 a = *(const bf16x8*)(kv_bf + arow*1024 + k0 + q*8);
    #pragma unroll
    for (int nt = 0; nt < 4; ++nt) {
      const int n = h*64 + nt*16 + l15;
      const bf16x8 bfr = *(const bf16x8*)(Wt + n*1024 + k0 + q*8);
      acc[nt] = __builtin_amdgcn_mfma_f32_16x16x32_bf16(a, bfr, acc[nt], 0, 0, 0);
    }
  }
  #pragma unroll
  for (int nt = 0; nt < 4; ++nt) {
    const int d = nt*16 + l15;
    #pragma unroll
    for (int r = 0; r < 4; ++r) {
      const int row = m0 + q*4 + r;
      if (row < 616) {
        const int b = (int)(((unsigned)row * 54472u) >> 22);   // row/77
        const int s = row - b*77;
        if (isK) K_ws[((b*8 + h)*80 + s)*64 + d] = f2bf(acc[nt][r]);
        else     V_ws[((b*8 + h)*64 + d)*96 + s] = f2bf(acc[nt][r]);
      }
    }
  }
}

// ---------------------------------------------------------------------------
// fused v3: 64 tokens/block, 8 waves (512 thr), 512 blocks, 1 block/CU.
// Wave w owns head w (j in [64w,64w+64)).
// Phase 0: query fp32 -> A-panel[tok][c] bf16, stride 330 (conflict-free reads).
// Phase 1: Q = A @ Wq_t^T; B-panel staged via gll16, double-buffered (stage
//          next while computing current), XOR-swizzled (q ^ ((j>>1)&3)).
//          Q -> Q_lds[tok][j] (stride 520), overlaying the dead A/B panels.
// Phase 2: per-wave attention (own head, 2 halves of 32 tok); O overwrites Q.
// Phase 3: out = Wo_t @ O^T; Wo panel staged dbuf+swizzled; fp32 epilogue.
// LDS: max(A 42.2K + 2xB 65.5K = 107.8K, Q 66.6K + P 53.2K = 119.8K) = 119,808 B.
// ---------------------------------------------------------------------------
__global__ __launch_bounds__(512, 2) void fused_kernel(
    const float* __restrict__ query, const short* __restrict__ Wq_t,
    const short* __restrict__ K_ws, const short* __restrict__ V_ws,
    const short* __restrict__ Wo_t, const float* __restrict__ bo,
    float* __restrict__ out) {
  const int t = threadIdx.x, w = t >> 6, lane = t & 63;
  const int l15 = lane & 15, q = lane >> 4;
  const int b = blockIdx.x >> 6;
  const int n0 = (blockIdx.x & 63) * 64;

  // shorts: A-panel @0 (64x330=21120) | B bufs @21120 (2x16384)
  //         Q_lds  @0 (64x520=33280)  | P @33280 (8x32x104=26624)
  //         Wo bufs @33280 (2x10240)
  __shared__ short S[59904];

  const f32x4 z = {0.f, 0.f, 0.f, 0.f};

  // ---------------- phase 0: query -> A-panel (transpose, bf16) ----------
  {
    const float* qb = query + (size_t)b * CC * NN + n0;
    #pragma unroll
    for (int i = 0; i < 10; ++i) {
      const int f = i * 512 + t;
      const int c = f >> 4, n4 = (f & 15) * 4;
      const f32x4 v = *(const f32x4*)(qb + (size_t)c * NN + n4);
      #pragma unroll
      for (int j = 0; j < 4; ++j)
        S[(n4 + j) * 330 + c] = f2bf(v[j]);
    }
  }

  // ---------------- phase 1: Q = A @ Wq^T (staged, dbuf, swizzled) -------
  {
    f32x4 acc[4][4];
    #pragma unroll
    for (int mt = 0; mt < 4; ++mt)
      #pragma unroll
      for (int nt = 0; nt < 4; ++nt) acc[mt][nt] = z;

    auto stageB = [&](int it, int pbuf) {
      const int k0 = it * 32;
      short* dstb = S + 21120 + pbuf * 16384;
      #pragma unroll
      for (int p = 0; p < 4; ++p) {
        const int L = p * 512 + t;              // 16-B slot
        const int j = L >> 2, qp = L & 3;
        const int ql = qp ^ ((j >> 1) & 3);     // involution
        gll16(dstb + L * 8, Wq_t + (size_t)j * 320 + k0 + ql * 8);
      }
    };

    stageB(0, 0);
    __syncthreads();   // A-panel + buf0 ready
    for (int it = 0; it < 10; ++it) {
      if (it + 1 < 10) stageB(it + 1, (it + 1) & 1);
      const int k0 = it * 32;
      const short* Bb = S + 21120 + (it & 1) * 16384;
      bf16x8 a[4], bb[4];
      #pragma unroll
      for (int mt = 0; mt < 4; ++mt)
        a[mt] = *(const bf16x8*)(S + (mt * 16 + l15) * 330 + k0 + q * 8);
      #pragma unroll
      for (int nt = 0; nt < 4; ++nt) {
        const int jr = w * 64 + nt * 16 + l15;
        const int a16 = jr * 4 + (q ^ ((jr >> 1) & 3));
        bb[nt] = *(const bf16x8*)(Bb + a16 * 8);
      }
      #pragma unroll
      for (int mt = 0; mt < 4; ++mt)
        #pragma unroll
        for (int nt = 0; nt < 4; ++nt)
          acc[mt][nt] = __builtin_amdgcn_mfma_f32_16x16x32_bf16(a[mt], bb[nt], acc[mt][nt], 0, 0, 0);
      __syncthreads();  // drains next-stage loads; frees buf for overwrite
    }
    // Q -> Q_lds (overlays dead A/B panels); all waves past final barrier.
    #pragma unroll
    for (int mt = 0; mt < 4; ++mt)
      #pragma unroll
      for (int r = 0; r < 4; ++r) {
        const int tok = mt * 16 + q * 4 + r;
        #pragma unroll
        for (int nt = 0; nt < 4; ++nt)
          S[tok * 520 + w * 64 + nt * 16 + l15] = f2bf(acc[mt][nt][r]);
      }
  }
  // no barrier: wave w reads only its own Q columns + private P scratch.

  // ---------------- phase 2: attention (wave w = head w, 2 halves) -------
  {
    short* scrw = S + 33280 + w * 3328;     // 32 x 104 bf16
    #pragma unroll
    for (int i = 0; i < 4; ++i) {           // zero P cols [80,96)
      const int f = lane + i * 64;
      *(unsigned*)(scrw + (f >> 3) * 104 + 80 + (f & 7) * 2) = 0u;
    }
    const short* __restrict__ Kh = K_ws + (size_t)(b * 8 + w) * 80 * 64;
    const short* __restrict__ Vh = V_ws + (size_t)(b * 8 + w) * 64 * 96;

    for (int g = 0; g < 2; ++g) {
      const int tb = g * 32;
      f32x4 qk[2][5];
      #pragma unroll
      for (int nt = 0; nt < 2; ++nt)
        #pragma unroll
        for (int st = 0; st < 5; ++st) qk[nt][st] = z;
      #pragma unroll
      for (int f = 0; f < 2; ++f) {
        bf16x8 bq[2];
        #pragma unroll
        for (int nt = 0; nt < 2; ++nt)
          bq[nt] = *(const bf16x8*)(S + (tb + nt * 16 + l15) * 520 + w * 64 + f * 32 + q * 8);
        #pragma unroll
        for (int st = 0; st < 5; ++st) {
          const bf16x8 a = *(const bf16x8*)(Kh + (st * 16 + l15) * 64 + f * 32 + q * 8);
          #pragma unroll
          for (int nt = 0; nt < 2; ++nt)
            qk[nt][st] = __builtin_amdgcn_mfma_f32_16x16x32_bf16(a, bq[nt], qk[nt][st], 0, 0, 0);
        }
      }

      #pragma unroll
      for (int nt = 0; nt < 2; ++nt) {
        float mx = -1e30f;
        #pragma unroll
        for (int st = 0; st < 5; ++st)
          #pragma unroll
          for (int r = 0; r < 4; ++r) {
            const int s = st * 16 + q * 4 + r;
            const float vv = (s < SKV) ? qk[nt][st][r] : -1e30f;
            qk[nt][st][r] = vv;
            mx = fmaxf(mx, vv);
          }
        mx = fmaxf(mx, __shfl_xor(mx, 16));
        mx = fmaxf(mx, __shfl_xor(mx, 32));
        float sum = 0.f;
        #pragma unroll
        for (int st = 0; st < 5; ++st)
          #pragma unroll
          for (int r = 0; r < 4; ++r) {
            const int s = st * 16 + q * 4 + r;
            const float e = (s < SKV) ? __expf(qk[nt][st][r] - mx) : 0.f;
            qk[nt][st][r] = e;
            sum += e;
          }
        sum += __shfl_xor(sum, 16);
        sum += __shfl_xor(sum, 32);
        const float inv = 1.0f / sum;
        #pragma unroll
        for (int st = 0; st < 5; ++st) {
          s16x4 pv;
          #pragma unroll
          for (int r = 0; r < 4; ++r) pv[r] = f2bf(qk[nt][st][r] * inv);
          *(s16x4*)(scrw + (nt * 16 + l15) * 104 + st * 16 + q * 4) = pv;
        }
      }

      f32x4 ov[2][4];
      #pragma unroll
      for (int nt = 0; nt < 2; ++nt)
        #pragma unroll
        for (int dt = 0; dt < 4; ++dt) ov[nt][dt] = z;
      #pragma unroll
      for (int f = 0; f < 3; ++f) {
        bf16x8 bp[2];
        #pragma unroll
        for (int nt = 0; nt < 2; ++nt)
          bp[nt] = *(const bf16x8*)(scrw + (nt * 16 + l15) * 104 + f * 32 + q * 8);
        #pragma unroll
        for (int dt = 0; dt < 4; ++dt) {
          const bf16x8 a = *(const bf16x8*)(Vh + (dt * 16 + l15) * 96 + f * 32 + q * 8);
          #pragma unroll
          for (int nt = 0; nt < 2; ++nt)
            ov[nt][dt] = __builtin_amdgcn_mfma_f32_16x16x32_bf16(a, bp[nt], ov[nt][dt], 0, 0, 0);
        }
      }
      // O overwrites Q in place (own columns, rows already consumed this half)
      #pragma unroll
      for (int nt = 0; nt < 2; ++nt)
        #pragma unroll
        for (int dt = 0; dt < 4; ++dt) {
          s16x4 pv;
          #pragma unroll
          for (int r = 0; r < 4; ++r) pv[r] = f2bf(ov[nt][dt][r]);
          *(s16x4*)(S + (tb + nt * 16 + l15) * 520 + w * 64 + dt * 16 + q * 4) = pv;
        }
    }
  }
  __syncthreads();   // O complete; P region free for Wo staging

  // ---------------- phase 3: out = Wo_t @ O^T + bias ---------------------
  {
    const int wm = w & 3;         // c-group: 80 channels
    const int wg = w >> 2;        // tok-group: 32 tokens
    f32x4 oc[5][2];
    #pragma unroll
    for (int mt = 0; mt < 5; ++mt)
      #pragma unroll
      for (int nt = 0; nt < 2; ++nt) oc[mt][nt] = z;

    auto stageW = [&](int it, int pbuf) {
      const int k0 = it * 32;
      short* dstb = S + 33280 + pbuf * 10240;
      #pragma unroll
      for (int p = 0; p < 3; ++p) {
        const int L = p * 512 + t;
        if (L < 1280) {
          const int j = L >> 2, qp = L & 3;
          const int ql = qp ^ ((j >> 1) & 3);
          gll16(dstb + L * 8, Wo_t + (size_t)j * 512 + k0 + ql * 8);
        }
      }
    };

    stageW(0, 0);
    __syncthreads();
    for (int it = 0; it < 16; ++it) {
      if (it + 1 < 16) stageW(it + 1, (it + 1) & 1);
      const int k0 = it * 32;
      const short* Wb = S + 33280 + (it & 1) * 10240;
      bf16x8 a[5], bb[2];
      #pragma unroll
      for (int mt = 0; mt < 5; ++mt) {
        const int jr = wm * 80 + mt * 16 + l15;
        const int a16 = jr * 4 + (q ^ ((jr >> 1) & 3));
        a[mt] = *(const bf16x8*)(Wb + a16 * 8);
      }
      #pragma unroll
      for (int nt = 0; nt < 2; ++nt)
        bb[nt] = *(const bf16x8*)(S + (wg * 32 + nt * 16 + l15) * 520 + k0 + q * 8);
      #pragma unroll
      for (int mt = 0; mt < 5; ++mt)
        #pragma unroll
        for (int nt = 0; nt < 2; ++nt)
          oc[mt][nt] = __builtin_amdgcn_mfma_f32_16x16x32_bf16(a[mt], bb[nt], oc[mt][nt], 0, 0, 0);
      if (it + 1 < 16) __syncthreads();
    }
    #pragma unroll
    for (int mt = 0; mt < 5; ++mt)
      #pragma unroll
      for (int r = 0; r < 4; ++r) {
        const int c = wm * 80 + mt * 16 + q * 4 + r;
        const float bv = bo[c];
        float* rowp = out + ((size_t)(b * CC + c)) * NN + n0 + wg * 32;
        #pragma unroll
        for (int nt = 0; nt < 2; ++nt)
          rowp[nt * 16 + l15] = oc[mt][nt][r] + bv;
      }
  }
}

// ---------------------------------------------------------------------------
extern "C" void kernel_launch(void* const* d_in, const int* in_sizes, int n_in,
                              void* d_out, int out_size, void* d_ws, size_t ws_size,
                              hipStream_t stream) {
  const float* query = (const float*)d_in[0];
  const float* kv    = (const float*)d_in[1];
  const float* Wq    = (const float*)d_in[2];
  const float* Wk    = (const float*)d_in[3];
  const float* Wv    = (const float*)d_in[4];
  const float* Wo    = (const float*)d_in[5];
  const float* bo    = (const float*)d_in[6];
  float* out = (float*)d_out;

  char* p = (char*)d_ws;
  short* K_ws  = (short*)(p);             //   819,200 B [8][8][80][64]
  short* V_ws  = (short*)(p +   819200);  //   983,040 B [8][8][64][96]
  short* Wq_t  = (short*)(p +  1802240);  //   327,680 B [512][320] (x SCALE)
  short* Wo_t  = (short*)(p +  2129920);  //   327,680 B [320][512]
  short* kv_bf = (short*)(p +  2457600);  //  1,261,568 B [616][1024]
  short* Wk_t  = (short*)(p +  3719168);  //  1,048,576 B [512][1024]
  short* Wv_t  = (short*)(p +  4767744);  //  1,048,576 B [512][1024]

  prep_kernel<<<1192, 256, 0, stream>>>(kv, Wk, Wv, Wq, Wo, kv_bf,
                                        Wk_t, Wv_t, Wq_t, Wo_t,
                                        (unsigned*)V_ws);
  kvproj_kernel<<<dim3(10, 16), 256, 0, stream>>>(kv_bf, Wk_t, Wv_t, K_ws, V_ws);
  fused_kernel<<<512, 512, 0, stream>>>(query, Wq_t, K_ws, V_ws, Wo_t, bo, out);
}

// Round 4
// 175.519 us; speedup vs baseline: 1.2039x; 1.0072x over previous
//
#include <hip/hip_runtime.h>
#include <hip/hip_bf16.h>
#include <stdint.h>

#define BB     8
#define CC     320
#define NN     4096
#define SKV    77
#define HEADS  8
#define INNER  512
#define SCALE  0.125f

typedef float f32x4  __attribute__((ext_vector_type(4)));
typedef short bf16x8 __attribute__((ext_vector_type(8)));
typedef short s16x4  __attribute__((ext_vector_type(4)));

static __device__ __forceinline__ short f2bf(float f) {
  unsigned u = __float_as_uint(f);
  return (short)((u + 0x7fffu + ((u >> 16) & 1u)) >> 16);
}

// async global->LDS 16B copy; LDS dest is wave-uniform base + lane*16.
static __device__ __forceinline__ void gll16(void* lds, const void* g) {
  auto gp = reinterpret_cast<const uint32_t __attribute__((address_space(1)))*>(
      reinterpret_cast<uintptr_t>(g));
  auto lp = reinterpret_cast<uint32_t __attribute__((address_space(3)))*>(
      reinterpret_cast<uintptr_t>(lds));
  __builtin_amdgcn_global_load_lds(gp, lp, 16, 0, 0);
}

// ---------------------------------------------------------------------------
// prep: kv->bf16 | Wk,Wv,Wq(x SCALE),Wo tiled transposes | zero V_ws pad.
// blocks: [0,616) kv | [616,872) Wk/Wv | [872,912) Wq | [912,952) Wo |
// [952,1192) zero V_ws
// ---------------------------------------------------------------------------
__global__ __launch_bounds__(256) void prep_kernel(
    const float* __restrict__ kv, const float* __restrict__ Wk,
    const float* __restrict__ Wv, const float* __restrict__ Wq,
    const float* __restrict__ Wo, short* __restrict__ kv_bf,
    short* __restrict__ Wk_t, short* __restrict__ Wv_t,
    short* __restrict__ Wq_t, short* __restrict__ Wo_t,
    unsigned* __restrict__ zero_base) {
  __shared__ float T[64 * 65];
  const int blk = blockIdx.x, t = threadIdx.x;
  if (blk < 616) {
    const int base = blk * 1024;
    #pragma unroll
    for (int i = 0; i < 4; ++i) kv_bf[base + i*256 + t] = f2bf(kv[base + i*256 + t]);
    return;
  }
  if (blk >= 952) {              // zero V_ws (pad cols read by PV must be 0)
    const int base = (blk - 952) * 1024;
    #pragma unroll
    for (int i = 0; i < 4; ++i) zero_base[base + i*256 + t] = 0u;
    return;
  }
  const float* src; short* dst; int RS, CS, kt, ct; float scl = 1.0f;
  if (blk < 872) {               // Wk/Wv: [1024][512] -> [512][1024]
    const int tile = blk - 616;
    const bool isK = tile < 128;
    const int tt = isK ? tile : tile - 128;
    src = isK ? Wk : Wv; dst = isK ? Wk_t : Wv_t;
    RS = 1024; CS = 512; kt = tt >> 3; ct = tt & 7;
  } else if (blk < 912) {        // Wq: [320][512] -> [512][320], x SCALE
    const int tt = blk - 872;
    src = Wq; dst = Wq_t; RS = 320; CS = 512; kt = tt >> 3; ct = tt & 7;
    scl = SCALE;
  } else {                       // Wo: [512][320] -> [320][512]
    const int tt = blk - 912;
    src = Wo; dst = Wo_t; RS = 512; CS = 320; kt = tt / 5; ct = tt % 5;
  }
  const int cl = t & 63, rb = t >> 6;
  #pragma unroll
  for (int i = 0; i < 16; ++i)
    T[(rb + i*4)*65 + cl] = src[(size_t)(kt*64 + rb + i*4)*CS + ct*64 + cl];
  __syncthreads();
  #pragma unroll
  for (int i = 0; i < 16; ++i) {
    const int nl = rb + i*4;
    dst[(size_t)(ct*64 + nl)*RS + kt*64 + cl] = f2bf(T[cl*65 + nl] * scl);
  }
}

// ---------------------------------------------------------------------------
// kvproj: [616,1024]bf16 @ Wk_t/Wv_t -> K_ws [b][h][80][64], V_ws [b][h][64][96]
// ---------------------------------------------------------------------------
__global__ __launch_bounds__(256) void kvproj_kernel(
    const short* __restrict__ kv_bf, const short* __restrict__ Wk_t,
    const short* __restrict__ Wv_t, short* __restrict__ K_ws,
    short* __restrict__ V_ws) {
  const int t = threadIdx.x, w = t >> 6, lane = t & 63;
  const int l15 = lane & 15, q = lane >> 4;
  const int m0 = (blockIdx.x * 4 + w) * 16;
  const int y = blockIdx.y;
  const bool isK = (y < 8);
  const int h = y & 7;
  const short* __restrict__ Wt = isK ? Wk_t : Wv_t;
  const int arow = (m0 + l15 < 616) ? (m0 + l15) : 615;

  const f32x4 z = {0.f, 0.f, 0.f, 0.f};
  f32x4 acc[4] = {z, z, z, z};
  for (int k0 = 0; k0 < 1024; k0 += 32) {
    const bf16x8 a = *(const bf16x8*)(kv_bf + arow*1024 + k0 + q*8);
    #pragma unroll
    for (int nt = 0; nt < 4; ++nt) {
      const int n = h*64 + nt*16 + l15;
      const bf16x8 bfr = *(const bf16x8*)(Wt + n*1024 + k0 + q*8);
      acc[nt] = __builtin_amdgcn_mfma_f32_16x16x32_bf16(a, bfr, acc[nt], 0, 0, 0);
    }
  }
  #pragma unroll
  for (int nt = 0; nt < 4; ++nt) {
    const int d = nt*16 + l15;
    #pragma unroll
    for (int r = 0; r < 4; ++r) {
      const int row = m0 + q*4 + r;
      if (row < 616) {
        const int b = (int)(((unsigned)row * 54472u) >> 22);   // row/77
        const int s = row - b*77;
        if (isK) K_ws[((b*8 + h)*80 + s)*64 + d] = f2bf(acc[nt][r]);
        else     V_ws[((b*8 + h)*64 + d)*96 + s] = f2bf(acc[nt][r]);
      }
    }
  }
}

// ---------------------------------------------------------------------------
// fused v4: 64 tokens/block, 8 waves, 512 blocks, 1 block/CU.
// KEY: no block barriers in the K-loops. Wave w stages ITS OWN weight rows
// (head w's 64 Wq rows; c-range wm's 80 Wo rows) into wave-private LDS
// slices, synced by wave-local counted s_waitcnt vmcnt(N). Waves free-run.
// Barriers: after phase 0, before Q-write overlay, before phase 3. (3 total)
// LDS (shorts): phase0/1: A[64][330] @0 (21120) | W1 slice @21120+w*4096
//               (2 bufs x 2048). post barrier-2 overlay: Q_lds[64][520] @0
//               (33280) | P/W3 slice @33280+w*5120 (P 3328 | W3 2x2560).
// Total 74240 shorts = 148,480 B.
// ---------------------------------------------------------------------------
__global__ __launch_bounds__(512) void fused_kernel(
    const float* __restrict__ query, const short* __restrict__ Wq_t,
    const short* __restrict__ K_ws, const short* __restrict__ V_ws,
    const short* __restrict__ Wo_t, const float* __restrict__ bo,
    float* __restrict__ out) {
  const int t = threadIdx.x, w = t >> 6, lane = t & 63;
  const int l15 = lane & 15, q = lane >> 4;
  const int b = blockIdx.x >> 6;
  const int n0 = (blockIdx.x & 63) * 64;

  __shared__ short S[74240];

  const f32x4 z = {0.f, 0.f, 0.f, 0.f};

  // ---------------- phase 0: query -> A-panel (transpose, bf16) ----------
  {
    const float* qb = query + (size_t)b * CC * NN + n0;
    #pragma unroll
    for (int i = 0; i < 10; ++i) {
      const int f = i * 512 + t;
      const int c = f >> 4, n4 = (f & 15) * 4;
      const f32x4 v = *(const f32x4*)(qb + (size_t)c * NN + n4);
      #pragma unroll
      for (int j = 0; j < 4; ++j)
        S[(n4 + j) * 330 + c] = f2bf(v[j]);
    }
  }
  __syncthreads();   // barrier-1: A-panel ready

  // ---------------- phase 1: Q = A @ Wq^T (wave-private staged) ----------
  {
    f32x4 acc[4][4];
    #pragma unroll
    for (int mt = 0; mt < 4; ++mt)
      #pragma unroll
      for (int nt = 0; nt < 4; ++nt) acc[mt][nt] = z;

    short* W1w = S + 21120 + w * 4096;
    const short* __restrict__ Wqw = Wq_t + (size_t)(w * 64) * 320;

    auto stage1 = [&](int it, int pbuf) {
      const int k0 = it * 32;
      short* dstb = W1w + pbuf * 2048;
      #pragma unroll
      for (int p = 0; p < 4; ++p) {
        const int L = p * 64 + lane;          // 16-B slot within slice
        const int j = L >> 2, qp = L & 3;
        const int ql = qp ^ ((j >> 1) & 3);   // involution
        gll16(dstb + L * 8, Wqw + (size_t)j * 320 + k0 + ql * 8);
      }
    };

    stage1(0, 0);
    for (int it = 0; it < 10; ++it) {
      if (it + 1 < 10) {
        stage1(it + 1, (it + 1) & 1);
        asm volatile("s_waitcnt vmcnt(4)" ::: "memory");  // stage(it) done
      } else {
        asm volatile("s_waitcnt vmcnt(0)" ::: "memory");
      }
      __builtin_amdgcn_sched_barrier(0);
      const int k0 = it * 32;
      const short* Bb = W1w + (it & 1) * 2048;
      bf16x8 a[4], bb[4];
      #pragma unroll
      for (int mt = 0; mt < 4; ++mt)
        a[mt] = *(const bf16x8*)(S + (mt * 16 + l15) * 330 + k0 + q * 8);
      #pragma unroll
      for (int nt = 0; nt < 4; ++nt) {
        const int jr = nt * 16 + l15;
        const int slot = jr * 4 + (q ^ ((jr >> 1) & 3));
        bb[nt] = *(const bf16x8*)(Bb + slot * 8);
      }
      #pragma unroll
      for (int mt = 0; mt < 4; ++mt)
        #pragma unroll
        for (int nt = 0; nt < 4; ++nt)
          acc[mt][nt] = __builtin_amdgcn_mfma_f32_16x16x32_bf16(a[mt], bb[nt], acc[mt][nt], 0, 0, 0);
    }
    __syncthreads();   // barrier-2: A/W1 dead everywhere; Q_lds overlay legal
    #pragma unroll
    for (int mt = 0; mt < 4; ++mt)
      #pragma unroll
      for (int r = 0; r < 4; ++r) {
        const int tok = mt * 16 + q * 4 + r;
        #pragma unroll
        for (int nt = 0; nt < 4; ++nt)
          S[tok * 520 + w * 64 + nt * 16 + l15] = f2bf(acc[mt][nt][r]);
      }
  }
  // no barrier: wave w reads only its own Q columns + private P scratch.

  // ---------------- phase 2: attention (wave w = head w, 2 halves) -------
  {
    short* scrw = S + 33280 + w * 5120;     // 32 x 104 bf16 (within slice)
    #pragma unroll
    for (int i = 0; i < 4; ++i) {           // zero P cols [80,96)
      const int f = lane + i * 64;
      *(unsigned*)(scrw + (f >> 3) * 104 + 80 + (f & 7) * 2) = 0u;
    }
    const short* __restrict__ Kh = K_ws + (size_t)(b * 8 + w) * 80 * 64;
    const short* __restrict__ Vh = V_ws + (size_t)(b * 8 + w) * 64 * 96;

    for (int g = 0; g < 2; ++g) {
      const int tb = g * 32;
      f32x4 qk[2][5];
      #pragma unroll
      for (int nt = 0; nt < 2; ++nt)
        #pragma unroll
        for (int st = 0; st < 5; ++st) qk[nt][st] = z;
      #pragma unroll
      for (int f = 0; f < 2; ++f) {
        bf16x8 bq[2];
        #pragma unroll
        for (int nt = 0; nt < 2; ++nt)
          bq[nt] = *(const bf16x8*)(S + (tb + nt * 16 + l15) * 520 + w * 64 + f * 32 + q * 8);
        #pragma unroll
        for (int st = 0; st < 5; ++st) {
          const bf16x8 a = *(const bf16x8*)(Kh + (st * 16 + l15) * 64 + f * 32 + q * 8);
          #pragma unroll
          for (int nt = 0; nt < 2; ++nt)
            qk[nt][st] = __builtin_amdgcn_mfma_f32_16x16x32_bf16(a, bq[nt], qk[nt][st], 0, 0, 0);
        }
      }

      #pragma unroll
      for (int nt = 0; nt < 2; ++nt) {
        float mx = -1e30f;
        #pragma unroll
        for (int st = 0; st < 5; ++st)
          #pragma unroll
          for (int r = 0; r < 4; ++r) {
            const int s = st * 16 + q * 4 + r;
            const float vv = (s < SKV) ? qk[nt][st][r] : -1e30f;
            qk[nt][st][r] = vv;
            mx = fmaxf(mx, vv);
          }
        mx = fmaxf(mx, __shfl_xor(mx, 16));
        mx = fmaxf(mx, __shfl_xor(mx, 32));
        float sum = 0.f;
        #pragma unroll
        for (int st = 0; st < 5; ++st)
          #pragma unroll
          for (int r = 0; r < 4; ++r) {
            const int s = st * 16 + q * 4 + r;
            const float e = (s < SKV) ? __expf(qk[nt][st][r] - mx) : 0.f;
            qk[nt][st][r] = e;
            sum += e;
          }
        sum += __shfl_xor(sum, 16);
        sum += __shfl_xor(sum, 32);
        const float inv = 1.0f / sum;
        #pragma unroll
        for (int st = 0; st < 5; ++st) {
          s16x4 pv;
          #pragma unroll
          for (int r = 0; r < 4; ++r) pv[r] = f2bf(qk[nt][st][r] * inv);
          *(s16x4*)(scrw + (nt * 16 + l15) * 104 + st * 16 + q * 4) = pv;
        }
      }

      f32x4 ov[2][4];
      #pragma unroll
      for (int nt = 0; nt < 2; ++nt)
        #pragma unroll
        for (int dt = 0; dt < 4; ++dt) ov[nt][dt] = z;
      #pragma unroll
      for (int f = 0; f < 3; ++f) {
        bf16x8 bp[2];
        #pragma unroll
        for (int nt = 0; nt < 2; ++nt)
          bp[nt] = *(const bf16x8*)(scrw + (nt * 16 + l15) * 104 + f * 32 + q * 8);
        #pragma unroll
        for (int dt = 0; dt < 4; ++dt) {
          const bf16x8 a = *(const bf16x8*)(Vh + (dt * 16 + l15) * 96 + f * 32 + q * 8);
          #pragma unroll
          for (int nt = 0; nt < 2; ++nt)
            ov[nt][dt] = __builtin_amdgcn_mfma_f32_16x16x32_bf16(a, bp[nt], ov[nt][dt], 0, 0, 0);
        }
      }
      // O overwrites Q in place (own columns; rows of this half already used)
      #pragma unroll
      for (int nt = 0; nt < 2; ++nt)
        #pragma unroll
        for (int dt = 0; dt < 4; ++dt) {
          s16x4 pv;
          #pragma unroll
          for (int r = 0; r < 4; ++r) pv[r] = f2bf(ov[nt][dt][r]);
          *(s16x4*)(S + (tb + nt * 16 + l15) * 520 + w * 64 + dt * 16 + q * 4) = pv;
        }
    }
  }
  __syncthreads();   // barrier-3: all O written; slices free for Wo staging

  // ---------------- phase 3: out = Wo_t @ O^T + bias (wave-private) ------
  {
    const int wm = w & 3;         // c-group: 80 channels
    const int wg = w >> 2;        // tok-group: 32 tokens
    f32x4 oc[5][2];
    #pragma unroll
    for (int mt = 0; mt < 5; ++mt)
      #pragma unroll
      for (int nt = 0; nt < 2; ++nt) oc[mt][nt] = z;

    short* W3w = S + 33280 + w * 5120;
    const short* __restrict__ Wow = Wo_t + (size_t)(wm * 80) * 512;

    auto stage3 = [&](int it, int pbuf) {
      const int k0 = it * 32;
      short* dstb = W3w + pbuf * 2560;
      #pragma unroll
      for (int p = 0; p < 5; ++p) {
        const int L = p * 64 + lane;          // 320 slots: 80 rows x 4
        const int j = L >> 2, qp = L & 3;
        const int ql = qp ^ ((j >> 1) & 3);
        gll16(dstb + L * 8, Wow + (size_t)j * 512 + k0 + ql * 8);
      }
    };

    stage3(0, 0);
    for (int it = 0; it < 16; ++it) {
      if (it + 1 < 16) {
        stage3(it + 1, (it + 1) & 1);
        asm volatile("s_waitcnt vmcnt(5)" ::: "memory");  // stage(it) done
      } else {
        asm volatile("s_waitcnt vmcnt(0)" ::: "memory");
      }
      __builtin_amdgcn_sched_barrier(0);
      const int k0 = it * 32;
      const short* Wb = W3w + (it & 1) * 2560;
      bf16x8 a[5], bb[2];
      #pragma unroll
      for (int mt = 0; mt < 5; ++mt) {
        const int r = mt * 16 + l15;
        const int slot = r * 4 + (q ^ ((r >> 1) & 3));
        a[mt] = *(const bf16x8*)(Wb + slot * 8);
      }
      #pragma unroll
      for (int nt = 0; nt < 2; ++nt)
        bb[nt] = *(const bf16x8*)(S + (wg * 32 + nt * 16 + l15) * 520 + k0 + q * 8);
      #pragma unroll
      for (int mt = 0; mt < 5; ++mt)
        #pragma unroll
        for (int nt = 0; nt < 2; ++nt)
          oc[mt][nt] = __builtin_amdgcn_mfma_f32_16x16x32_bf16(a[mt], bb[nt], oc[mt][nt], 0, 0, 0);
    }
    #pragma unroll
    for (int mt = 0; mt < 5; ++mt)
      #pragma unroll
      for (int r = 0; r < 4; ++r) {
        const int c = wm * 80 + mt * 16 + q * 4 + r;
        const float bv = bo[c];
        float* rowp = out + ((size_t)(b * CC + c)) * NN + n0 + wg * 32;
        #pragma unroll
        for (int nt = 0; nt < 2; ++nt)
          rowp[nt * 16 + l15] = oc[mt][nt][r] + bv;
      }
  }
}

// ---------------------------------------------------------------------------
extern "C" void kernel_launch(void* const* d_in, const int* in_sizes, int n_in,
                              void* d_out, int out_size, void* d_ws, size_t ws_size,
                              hipStream_t stream) {
  const float* query = (const float*)d_in[0];
  const float* kv    = (const float*)d_in[1];
  const float* Wq    = (const float*)d_in[2];
  const float* Wk    = (const float*)d_in[3];
  const float* Wv    = (const float*)d_in[4];
  const float* Wo    = (const float*)d_in[5];
  const float* bo    = (const float*)d_in[6];
  float* out = (float*)d_out;

  char* p = (char*)d_ws;
  short* K_ws  = (short*)(p);             //   819,200 B [8][8][80][64]
  short* V_ws  = (short*)(p +   819200);  //   983,040 B [8][8][64][96]
  short* Wq_t  = (short*)(p +  1802240);  //   327,680 B [512][320] (x SCALE)
  short* Wo_t  = (short*)(p +  2129920);  //   327,680 B [320][512]
  short* kv_bf = (short*)(p +  2457600);  //  1,261,568 B [616][1024]
  short* Wk_t  = (short*)(p +  3719168);  //  1,048,576 B [512][1024]
  short* Wv_t  = (short*)(p +  4767744);  //  1,048,576 B [512][1024]

  prep_kernel<<<1192, 256, 0, stream>>>(kv, Wk, Wv, Wq, Wo, kv_bf,
                                        Wk_t, Wv_t, Wq_t, Wo_t,
                                        (unsigned*)V_ws);
  kvproj_kernel<<<dim3(10, 16), 256, 0, stream>>>(kv_bf, Wk_t, Wv_t, K_ws, V_ws);
  fused_kernel<<<512, 512, 0, stream>>>(query, Wq_t, K_ws, V_ws, Wo_t, bo, out);
}